// Round 7
// baseline (186.974 us; speedup 1.0000x reference)
//
#include <hip/hip_runtime.h>
#include <cstddef>
#include <cstdint>

#define LEAKY(s) ((s) >= 0.f ? (s) : 0.1f * (s))

constexpr int PTS    = 4096;   // H*W
constexpr int NBATCH = 32;
constexpr int NM     = 8;      // regions
constexpr int TILE   = 64;     // points per block in kA
constexpr int NTILES = PTS / TILE;  // 64

// ---------------- workspace layout (bytes) ----------------
constexpr size_t OFF_XS   = 0;        // xs (B,128,8) f32 128KB ; y (B,1024) aliases after kC
constexpr size_t OFF_IDX  = 131072;   // idx (B,128,8) i32 128KB ; h1 aliases after kC
constexpr size_t OFF_POOL = 262144;   // pool (B,1024) u32 (enc f32) 128KB
constexpr size_t OFF_WSP  = 393216;   // split weights w2h/w2l/w3h/w3l 128KB
constexpr size_t OFF_Y64  = 524288;   // y64 (B,64,1024) f32 8MB

using bf16x8 = __attribute__((ext_vector_type(8))) short;
using f32x4v = __attribute__((ext_vector_type(4))) float;
using u16x4  = __attribute__((ext_vector_type(4))) unsigned short;
using u16x8  = __attribute__((ext_vector_type(8))) unsigned short;

// split f32 -> bf16 hi (truncate) + bf16 lo (RNE of remainder): x ~ hi + lo
__device__ __forceinline__ void splitbf(float x, unsigned short& h, unsigned short& l) {
  unsigned u = __float_as_uint(x);
  unsigned short hh = (unsigned short)(u >> 16);
  float r = x - __uint_as_float((unsigned)hh << 16);
  unsigned v = __float_as_uint(r);
  unsigned rr = (v + 0x7FFFu + ((v >> 16) & 1u)) >> 16;
  h = hh; l = (unsigned short)rr;
}

// monotone f32 <-> u32 encoding (order-preserving) for atomicMax pooling
__device__ __forceinline__ unsigned encf(float f) {
  unsigned u = __float_as_uint(f);
  return (u & 0x80000000u) ? ~u : (u | 0x80000000u);
}
__device__ __forceinline__ float decf(unsigned e) {
  unsigned u = (e & 0x80000000u) ? (e ^ 0x80000000u) : ~e;
  return __uint_as_float(u);
}

// swizzled byte offset into Xt[pt][k] bf16 arrays (row = 256B): XOR bits 4..6 by pt&7
__device__ __forceinline__ int swzb(int pt, int kByte) {
  return pt * 256 + (kByte ^ ((pt & 7) << 4));
}

// ============================================================
// Kernel W: pre-split w2/w3 into bf16 hi/lo planes in A-fragment order:
// elem = (((mt*4+kt)*4+l4)*16+l15)*8+e ; c=mt*16+l15, k=kt*32+l4*8+e
// ============================================================
__global__ __launch_bounds__(256) void kW(const float* __restrict__ w2,
                                          const float* __restrict__ w3,
                                          unsigned short* __restrict__ wsp) {
  int id = blockIdx.x * 256 + threadIdx.x;   // 0..32767
  int layer = id >> 14, e16 = id & 16383;
  int e = e16 & 7, l15 = (e16 >> 3) & 15, l4 = (e16 >> 7) & 3,
      kt = (e16 >> 9) & 3, mt = e16 >> 11;
  int c = mt * 16 + l15, k = kt * 32 + l4 * 8 + e;
  float v = (layer ? w3 : w2)[c * 128 + k];
  unsigned short h, l;
  splitbf(v, h, l);
  wsp[layer * 32768 + e16] = h;
  wsp[layer * 32768 + 16384 + e16] = l;
}

// ============================================================
// Kernel A: conv1 -> conv2 -> conv3 (split-bf16 MFMA) -> masked-max ->
// atomicMax pool. grid (NTILES=64, B), 256 thr, 34KB LDS -> 4 blocks/CU.
// ============================================================
__device__ __forceinline__ void mfmaLayer(const unsigned short* __restrict__ Wh,
                                          const unsigned short* __restrict__ Wl,
                                          const float* __restrict__ bias,
                                          const char* XHc, const char* XLc,
                                          int lane, int mt0, f32x4v acc[2][4]) {
  const int l15 = lane & 15, l4 = lane >> 4;
#pragma unroll
  for (int mi = 0; mi < 2; mi++) {
    float4 bv = *(const float4*)(bias + (mt0 + mi) * 16 + l4 * 4);
    f32x4v b4; b4[0] = bv.x; b4[1] = bv.y; b4[2] = bv.z; b4[3] = bv.w;
#pragma unroll
    for (int nt = 0; nt < 4; nt++) acc[mi][nt] = b4;
  }
#pragma unroll
  for (int kt = 0; kt < 4; kt++) {
    bf16x8 ah[2], al[2];
#pragma unroll
    for (int mi = 0; mi < 2; mi++) {
      int off = ((((mt0 + mi) * 4 + kt) * 4 + l4) * 16 + l15) * 8;
      ah[mi] = *(const bf16x8*)(Wh + off);
      al[mi] = *(const bf16x8*)(Wl + off);
    }
    const int kb = (kt * 32 + l4 * 8) * 2;
#pragma unroll
    for (int nt = 0; nt < 4; nt++) {
      const int off = swzb(nt * 16 + l15, kb);
      bf16x8 bh = *(const bf16x8*)(XHc + off);
      bf16x8 bl = *(const bf16x8*)(XLc + off);
#pragma unroll
      for (int mi = 0; mi < 2; mi++) {
        acc[mi][nt] = __builtin_amdgcn_mfma_f32_16x16x32_bf16(ah[mi], bh, acc[mi][nt], 0, 0, 0);
        acc[mi][nt] = __builtin_amdgcn_mfma_f32_16x16x32_bf16(ah[mi], bl, acc[mi][nt], 0, 0, 0);
        acc[mi][nt] = __builtin_amdgcn_mfma_f32_16x16x32_bf16(al[mi], bh, acc[mi][nt], 0, 0, 0);
      }
    }
  }
}

__global__ __launch_bounds__(256, 4) void kA(
    const float* __restrict__ coor, const float* __restrict__ region,
    const float* __restrict__ extents,
    const float* __restrict__ w1, const float* __restrict__ b1,
    const float* __restrict__ b2, const float* __restrict__ b3,
    const unsigned short* __restrict__ wsp,
    unsigned* __restrict__ pool) {
  __shared__ unsigned short XH[TILE * 128];  // 16KB (f32 funnel aliases in epilogue)
  __shared__ unsigned short XL[TILE * 128];  // 16KB
  __shared__ float reg_s[NM * TILE];         // 2KB
  const int tid = threadIdx.x;
  const int b = blockIdx.y;
  const int t0 = blockIdx.x * TILE;
  const int lane = tid & 63;
  const int wv = tid >> 6;
  char* XHc = (char*)XH;
  char* XLc = (char*)XL;

  if (tid < 128) {  // stage region tile: 8 rows x 64
    int m = tid >> 4, j = tid & 15;
    float4 v = *(const float4*)(region + ((size_t)b * NM + m) * PTS + t0 + j * 4);
    *(float4*)(reg_s + m * TILE + j * 4) = v;
  }
  {  // layer 1 (K=5): thread = (pt, ch-quarter); writes Xt bf16 hi/lo
    const int pt = tid & 63;
    const int ch0 = (tid >> 6) * 32;
    float e0 = extents[b * 3], e1 = extents[b * 3 + 1], e2 = extents[b * 3 + 2];
    float in5[5];
#pragma unroll
    for (int i = 0; i < 5; i++) in5[i] = coor[((size_t)b * 5 + i) * PTS + t0 + pt];
    in5[0] = (in5[0] - 0.5f) * e0;
    in5[1] = (in5[1] - 0.5f) * e1;
    in5[2] = (in5[2] - 0.5f) * e2;
#pragma unroll
    for (int c8 = 0; c8 < 32; c8 += 8) {
      u16x8 hh, ll;
#pragma unroll
      for (int q = 0; q < 8; q++) {
        int c = ch0 + c8 + q;
        float s = b1[c];
#pragma unroll
        for (int i = 0; i < 5; i++) s = fmaf(w1[c * 5 + i], in5[i], s);
        s = LEAKY(s);
        unsigned short h, l;
        splitbf(s, h, l);
        hh[q] = h; ll[q] = l;
      }
      int off = swzb(pt, (ch0 + c8) * 2);
      *(u16x8*)(XHc + off) = hh;
      *(u16x8*)(XLc + off) = ll;
    }
  }
  __syncthreads();

  f32x4v acc[2][4];
  const int mt0 = wv * 2;
  const int l15 = lane & 15, l4 = lane >> 4;

  // layer 2
  mfmaLayer(wsp, wsp + 16384, b2, XHc, XLc, lane, mt0, acc);
  __syncthreads();
  {  // leaky + split + write act2 back to Xt
#pragma unroll
    for (int mi = 0; mi < 2; mi++) {
      const int ch0 = (mt0 + mi) * 16 + l4 * 4;
#pragma unroll
      for (int nt = 0; nt < 4; nt++) {
        u16x4 h4, l4v;
#pragma unroll
        for (int r = 0; r < 4; r++) {
          float s = acc[mi][nt][r];
          s = LEAKY(s);
          unsigned short h, l;
          splitbf(s, h, l);
          h4[r] = h; l4v[r] = l;
        }
        int off = swzb(nt * 16 + l15, ch0 * 2);
        *(u16x4*)(XHc + off) = h4;
        *(u16x4*)(XLc + off) = l4v;
      }
    }
  }
  __syncthreads();
  // layer 3 (bias, no activation)
  mfmaLayer(wsp + 32768, wsp + 49152, b3, XHc, XLc, lane, mt0, acc);
  __syncthreads();  // all reads done; reuse XH as f32 funnel

  {  // region-masked max -> funnel[c*8+m]
    float* funnel = (float*)XH;
#pragma unroll
    for (int m = 0; m < NM; m++) {
      float rv[4];
#pragma unroll
      for (int nt = 0; nt < 4; nt++) rv[nt] = reg_s[m * TILE + nt * 16 + l15];
#pragma unroll
      for (int mi = 0; mi < 2; mi++)
#pragma unroll
        for (int r = 0; r < 4; r++) {
          float mx = acc[mi][0][r] * rv[0];
#pragma unroll
          for (int nt = 1; nt < 4; nt++) mx = fmaxf(mx, acc[mi][nt][r] * rv[nt]);
          mx = fmaxf(mx, __shfl_xor(mx, 1));
          mx = fmaxf(mx, __shfl_xor(mx, 2));
          mx = fmaxf(mx, __shfl_xor(mx, 4));
          mx = fmaxf(mx, __shfl_xor(mx, 8));
          if (l15 == 0) funnel[((mt0 + mi) * 16 + l4 * 4 + r) * 8 + m] = mx;
        }
    }
  }
  __syncthreads();
  {  // order-independent pool: atomicMax of monotone-encoded f32
    const float* fun = (const float*)XH;
    float4 v = *(const float4*)(fun + tid * 4);
    unsigned* pl = pool + (size_t)b * 1024 + tid * 4;
    atomicMax(pl + 0, encf(v.x));
    atomicMax(pl + 1, encf(v.y));
    atomicMax(pl + 2, encf(v.z));
    atomicMax(pl + 3, encf(v.w));
  }
}

// ============================================================
// Kernel B: decode pool -> softmax over channels per m -> per-(b,c) sort.
// grid (B), 256 thr.
// ============================================================
__global__ __launch_bounds__(256) void kB(const unsigned* __restrict__ pool,
                                          float* __restrict__ xs,
                                          int* __restrict__ idx) {
  __shared__ float pl[1024];
  __shared__ float xsl[1024];
  int b = blockIdx.x, tid = threadIdx.x;
#pragma unroll
  for (int q = 0; q < 4; q++) {
    int p = tid + q * 256;
    pl[p] = decf(pool[(size_t)b * 1024 + p]);
  }
  __syncthreads();
  int m = tid >> 5, lane = tid & 31;
  float v[4];
#pragma unroll
  for (int j = 0; j < 4; j++) v[j] = pl[(lane + 32 * j) * 8 + m];
  float mx = fmaxf(fmaxf(v[0], v[1]), fmaxf(v[2], v[3]));
#pragma unroll
  for (int d = 1; d < 32; d <<= 1) mx = fmaxf(mx, __shfl_xor(mx, d, 32));
  float e[4]; float s = 0.f;
#pragma unroll
  for (int j = 0; j < 4; j++) { e[j] = expf(v[j] - mx); s += e[j]; }
#pragma unroll
  for (int d = 1; d < 32; d <<= 1) s += __shfl_xor(s, d, 32);
#pragma unroll
  for (int j = 0; j < 4; j++) {
    float x = e[j] / s;
    int c = lane + 32 * j;
    xsl[c * 8 + m] = x;
    xs[(size_t)b * 1024 + c * 8 + m] = x;
  }
  __syncthreads();
  if (tid < 128) {
    float vv[8];
#pragma unroll
    for (int n = 0; n < 8; n++) vv[n] = xsl[tid * 8 + n];
    int used = 0;
#pragma unroll
    for (int n = 0; n < 8; n++) {
      int best = 0; float bvv = -1.f;
#pragma unroll
      for (int q = 0; q < 8; q++) {
        bool ok = ((used >> q) & 1) == 0;
        if (ok && vv[q] > bvv) { bvv = vv[q]; best = q; }  // strict > == lowest-index tie-break
      }
      used |= 1 << best;
      idx[(size_t)b * 1024 + tid * 8 + n] = best;
    }
  }
}

// ============================================================
// Kernel C: GEMM D[b,k,m,o] = sum_c xs[b,c,m]*w_sp[o,c,k] + fused gather-sum.
// grid (64 ktiles of 2, 8 bgroups of 4), 256 thr, 2 blocks/CU.
// As padded stride 260 to avoid staging-write bank conflicts.
// ============================================================
__global__ __launch_bounds__(256) void kC(const float* __restrict__ xs,
                                          const float* __restrict__ w_sp,
                                          const int* __restrict__ idx,
                                          float* __restrict__ y64) {
  __shared__ float As[16 * 260];  // [cc][row=kk*128+o], pad 4
  __shared__ float Bs[16 * 32];
  __shared__ int idxL[4][2][8];   // [bl][kk][r]
  const int tid = threadIdx.x;
  const int k0 = blockIdx.x * 2;
  const int bbase = blockIdx.y * 4;
  const int rg = tid & 63, cgq = tid >> 6;
  const int j0 = cgq * 8;
  if (tid < 64) {
    int bl = tid >> 4, kk = (tid >> 3) & 1, r = tid & 7;
    idxL[bl][kk][r] = idx[(size_t)(bbase + bl) * 1024 + (k0 + kk) * 8 + r];
  }
  float acc[4][8];
#pragma unroll
  for (int i = 0; i < 4; i++)
#pragma unroll
    for (int j = 0; j < 8; j++) acc[i][j] = 0.f;

  for (int c0 = 0; c0 < 128; c0 += 16) {
    __syncthreads();
#pragma unroll
    for (int it = 0; it < 8; it++) {
      int q = tid + it * 256;             // 0..2047
      int o = q >> 4, cc = q & 15;
      float2 w = *(const float2*)(w_sp + (size_t)o * 16384 + (size_t)(c0 + cc) * 128 + k0);
      As[cc * 260 + o]       = w.x;
      As[cc * 260 + 128 + o] = w.y;
    }
#pragma unroll
    for (int it = 0; it < 2; it++) {
      int f = tid + it * 256;             // 0..511 = bl*128 + cc*8 + m
      int bl = f >> 7, rem = f & 127;
      Bs[(rem >> 3) * 32 + bl * 8 + (rem & 7)] =
          xs[((size_t)(bbase + bl) * 128 + c0 + (rem >> 3)) * 8 + (rem & 7)];
    }
    __syncthreads();
#pragma unroll
    for (int cc = 0; cc < 16; cc++) {
      float4 a = *(const float4*)(As + cc * 260 + rg * 4);
      float4 p0 = *(const float4*)(Bs + cc * 32 + j0);
      float4 p1 = *(const float4*)(Bs + cc * 32 + j0 + 4);
      float av[4] = {a.x, a.y, a.z, a.w};
      float bv[8] = {p0.x, p0.y, p0.z, p0.w, p1.x, p1.y, p1.z, p1.w};
#pragma unroll
      for (int i = 0; i < 4; i++)
#pragma unroll
        for (int j = 0; j < 8; j++) acc[i][j] = fmaf(av[i], bv[j], acc[i][j]);
    }
  }
  // gather-sum epilogue: row = rg*4+i -> kk = rg>>5, o = row&127; col j -> m.
  const int kk = rg >> 5;
  int ms[8];
#pragma unroll
  for (int r = 0; r < 8; r++) ms[r] = idxL[cgq][kk][r];
  float yp[4][8];
#pragma unroll
  for (int i4 = 0; i4 < 4; i4++) {
#pragma unroll
    for (int r = 0; r < 8; r++) {
      float v = 0.f;
#pragma unroll
      for (int j = 0; j < 8; j++) v += (j == ms[r]) ? acc[i4][j] : 0.f;
      yp[i4][r] = v;
    }
  }
#pragma unroll
  for (int i4 = 0; i4 < 4; i4++)
#pragma unroll
    for (int r = 0; r < 8; r++) yp[i4][r] += __shfl_xor(yp[i4][r], 32);
  if (rg < 32) {  // lane rg holds o = rg*4+i4, summed over both kk
    float* dst = y64 + ((size_t)(bbase + cgq) * 64 + blockIdx.x) * 1024 + rg * 32;
#pragma unroll
    for (int i4 = 0; i4 < 4; i4++) {
      float4 v0 = {yp[i4][0], yp[i4][1], yp[i4][2], yp[i4][3]};
      float4 v1 = {yp[i4][4], yp[i4][5], yp[i4][6], yp[i4][7]};
      *(float4*)(dst + i4 * 8) = v0;
      *(float4*)(dst + i4 * 8 + 4) = v1;
    }
  }
}

// ============================================================
// Kernel Y: y[b][f] = leaky(sum_{t<64} y64[b][t][f] + b_sp[f>>3]). grid (B).
// ============================================================
__global__ __launch_bounds__(256) void kY(const float* __restrict__ y64,
                                          const float* __restrict__ b_sp,
                                          float* __restrict__ y) {
  int b = blockIdx.x, tid = threadIdx.x;
  int f0 = tid * 4;
  const float* base = y64 + (size_t)b * 65536 + f0;
  float s0 = 0, s1 = 0, s2 = 0, s3 = 0;
#pragma unroll 8
  for (int t = 0; t < 64; t++) {
    float4 u = *(const float4*)(base + (size_t)t * 1024);
    s0 += u.x; s1 += u.y; s2 += u.z; s3 += u.w;
  }
  float v[4] = {s0, s1, s2, s3};
  float o[4];
#pragma unroll
  for (int j = 0; j < 4; j++) {
    int f = f0 + j;
    float s = v[j] + b_sp[f >> 3];
    o[j] = LEAKY(s);
  }
  float4 vv = {o[0], o[1], o[2], o[3]};
  *(float4*)(y + (size_t)b * 1024 + f0) = vv;
}

// ============================================================
// Kernel E1: fc1. grid (og 8, bq 8), 256 thr; wave w -> batch bq*4+w,
// y preloaded in 4 float4 regs; weight rows L1-shared across waves.
// ============================================================
__global__ __launch_bounds__(256) void kE1(
    const float* __restrict__ y, const float* __restrict__ fc1_w,
    const float* __restrict__ fc1_b, float* __restrict__ h1) {
  int og = blockIdx.x, bq = blockIdx.y, tid = threadIdx.x;
  int w = tid >> 6, lane = tid & 63;
  int b = bq * 4 + w;
  const float4* yv = (const float4*)(y + (size_t)b * 1024);
  float4 u[4];
#pragma unroll
  for (int r = 0; r < 4; r++) u[r] = yv[r * 64 + lane];
  for (int pass = 0; pass < 64; pass++) {
    int o = og * 64 + pass;
    const float4* wr = (const float4*)(fc1_w + (size_t)o * 1024);
    float sa = 0, sb = 0, sc = 0, sd = 0;
#pragma unroll
    for (int r = 0; r < 4; r++) {
      float4 wv = wr[r * 64 + lane];
      sa = fmaf(wv.x, u[r].x, sa); sb = fmaf(wv.y, u[r].y, sb);
      sc = fmaf(wv.z, u[r].z, sc); sd = fmaf(wv.w, u[r].w, sd);
    }
    float s = (sa + sb) + (sc + sd);
#pragma unroll
    for (int d = 1; d < 64; d <<= 1) s += __shfl_xor(s, d);
    if (lane == 0) {
      float t = s + fc1_b[o];
      h1[(size_t)b * 512 + o] = LEAKY(t);
    }
  }
}

// ============================================================
// Kernel E2: fc2 -> heads. grid (B), 256 thr.
// ============================================================
__global__ __launch_bounds__(256) void kE2(
    const float* __restrict__ h1, const float* __restrict__ fc2_w,
    const float* __restrict__ fc2_b,
    const float* __restrict__ fcr_w, const float* __restrict__ fcr_b,
    const float* __restrict__ fct_w, const float* __restrict__ fct_b,
    float* __restrict__ out) {
  __shared__ float h1l[512];
  __shared__ float h2[256];
  int b = blockIdx.x, tid = threadIdx.x;
  if (tid < 128) {
    float4 v = *(const float4*)(h1 + (size_t)b * 512 + tid * 4);
    *(float4*)(h1l + tid * 4) = v;
  }
  __syncthreads();
  {
    int o = tid;
    const float4* wr = (const float4*)(fc2_w + (size_t)o * 512);
    const float4* uv = (const float4*)h1l;
    float sa = 0, sb = 0, sc = 0, sd = 0;
#pragma unroll 4
    for (int q = 0; q < 128; q++) {
      float4 w = wr[q];
      float4 u = uv[q];
      sa = fmaf(w.x, u.x, sa); sb = fmaf(w.y, u.y, sb);
      sc = fmaf(w.z, u.z, sc); sd = fmaf(w.w, u.w, sd);
    }
    float s = (sa + sb) + (sc + sd) + fc2_b[o];
    h2[o] = LEAKY(s);
  }
  __syncthreads();
  if (tid < 7) {
    bool isrot = tid < 4;
    int o = isrot ? tid : tid - 4;
    const float4* wr = (const float4*)((isrot ? fcr_w : fct_w) + (size_t)o * 256);
    const float4* uv = (const float4*)h2;
    float sa = 0, sb = 0, sc = 0, sd = 0;
#pragma unroll 4
    for (int q = 0; q < 64; q++) {
      float4 w = wr[q];
      float4 u = uv[q];
      sa = fmaf(w.x, u.x, sa); sb = fmaf(w.y, u.y, sb);
      sc = fmaf(w.z, u.z, sc); sd = fmaf(w.w, u.w, sd);
    }
    float s = (sa + sb) + (sc + sd) + (isrot ? fcr_b[o] : fct_b[o]);
    out[isrot ? (b * 4 + o) : (128 + b * 3 + o)] = s;
  }
}

extern "C" void kernel_launch(void* const* d_in, const int* in_sizes, int n_in,
                              void* d_out, int out_size, void* d_ws, size_t ws_size,
                              hipStream_t stream) {
  const float* coor    = (const float*)d_in[0];
  const float* region  = (const float*)d_in[1];
  const float* extents = (const float*)d_in[2];
  const float* w1 = (const float*)d_in[3];  const float* b1 = (const float*)d_in[4];
  const float* w2 = (const float*)d_in[5];  const float* b2 = (const float*)d_in[6];
  const float* w3 = (const float*)d_in[7];  const float* b3 = (const float*)d_in[8];
  const float* w_sp = (const float*)d_in[9];  const float* b_sp = (const float*)d_in[10];
  const float* fc1_w = (const float*)d_in[11]; const float* fc1_b = (const float*)d_in[12];
  const float* fc2_w = (const float*)d_in[13]; const float* fc2_b = (const float*)d_in[14];
  const float* fcr_w = (const float*)d_in[15]; const float* fcr_b = (const float*)d_in[16];
  const float* fct_w = (const float*)d_in[17]; const float* fct_b = (const float*)d_in[18];

  char* ws = (char*)d_ws;
  float* xs   = (float*)(ws + OFF_XS);
  int*   idx  = (int*)(ws + OFF_IDX);
  unsigned* pool = (unsigned*)(ws + OFF_POOL);
  unsigned short* wsp = (unsigned short*)(ws + OFF_WSP);
  float* y64  = (float*)(ws + OFF_Y64);
  float* y    = (float*)(ws + OFF_XS);   // aliases xs: written after kC consumed xs
  float* h1   = (float*)(ws + OFF_IDX);  // aliases idx: written after kC consumed idx
  float* out  = (float*)d_out;

  hipMemsetAsync(pool, 0, (size_t)NBATCH * 1024 * 4, stream);  // enc(x) > 0 for finite x
  kW<<<dim3(128), 256, 0, stream>>>(w2, w3, wsp);
  kA<<<dim3(NTILES, NBATCH), 256, 0, stream>>>(coor, region, extents,
                                               w1, b1, b2, b3, wsp, pool);
  kB<<<dim3(NBATCH), 256, 0, stream>>>(pool, xs, idx);
  kC<<<dim3(64, 8), 256, 0, stream>>>(xs, w_sp, idx, y64);
  kY<<<dim3(NBATCH), 256, 0, stream>>>(y64, b_sp, y);
  kE1<<<dim3(8, 8), 256, 0, stream>>>(y, fc1_w, fc1_b, h1);
  kE2<<<dim3(NBATCH), 256, 0, stream>>>(h1, fc2_w, fc2_b, fcr_w, fcr_b,
                                        fct_w, fct_b, out);
}

// Round 8
// 154.768 us; speedup vs baseline: 1.2081x; 1.2081x over previous
//
#include <hip/hip_runtime.h>
#include <cstddef>
#include <cstdint>

#define LEAKY(s) ((s) >= 0.f ? (s) : 0.1f * (s))

constexpr int PTS    = 4096;   // H*W
constexpr int NBATCH = 32;
constexpr int NM     = 8;      // regions
constexpr int TILE   = 128;    // points per block in kA
constexpr int NTILES = PTS / TILE;  // 32

// ---------------- workspace layout (bytes) ----------------
constexpr size_t OFF_POOL = 0;        // pool (B,1024) u32 (enc f32) 128KB
constexpr size_t OFF_WSP  = 131072;   // split weights w2h/w2l/w3h/w3l 128KB
constexpr size_t OFF_Y32  = 262144;   // y32 (B,32,1024) f32 4MB

using bf16x8 = __attribute__((ext_vector_type(8))) short;
using f32x4v = __attribute__((ext_vector_type(4))) float;
using u16x4  = __attribute__((ext_vector_type(4))) unsigned short;
using u16x8  = __attribute__((ext_vector_type(8))) unsigned short;

// split f32 -> bf16 hi (truncate) + bf16 lo (RNE of remainder): x ~ hi + lo
__device__ __forceinline__ void splitbf(float x, unsigned short& h, unsigned short& l) {
  unsigned u = __float_as_uint(x);
  unsigned short hh = (unsigned short)(u >> 16);
  float r = x - __uint_as_float((unsigned)hh << 16);
  unsigned v = __float_as_uint(r);
  unsigned rr = (v + 0x7FFFu + ((v >> 16) & 1u)) >> 16;
  h = hh; l = (unsigned short)rr;
}

// monotone f32 <-> u32 encoding (order-preserving) for atomicMax pooling
__device__ __forceinline__ unsigned encf(float f) {
  unsigned u = __float_as_uint(f);
  return (u & 0x80000000u) ? ~u : (u | 0x80000000u);
}
__device__ __forceinline__ float decf(unsigned e) {
  unsigned u = (e & 0x80000000u) ? (e ^ 0x80000000u) : ~e;
  return __uint_as_float(u);
}

// swizzled byte offset into Xt[pt][k] bf16 arrays (row = 256B): XOR bits 4..6 by pt&7
__device__ __forceinline__ int swzb(int pt, int kByte) {
  return pt * 256 + (kByte ^ ((pt & 7) << 4));
}

// ============================================================
// Kernel W: pre-split w2/w3 into bf16 hi/lo planes in A-fragment order
// AND zero the pool (1 word per thread). grid(128),256.
// elem = (((mt*4+kt)*4+l4)*16+l15)*8+e ; c=mt*16+l15, k=kt*32+l4*8+e
// ============================================================
__global__ __launch_bounds__(256) void kW(const float* __restrict__ w2,
                                          const float* __restrict__ w3,
                                          unsigned short* __restrict__ wsp,
                                          unsigned* __restrict__ pool) {
  int id = blockIdx.x * 256 + threadIdx.x;   // 0..32767
  pool[id] = 0u;                             // enc(x) > 0 for all finite x
  int layer = id >> 14, e16 = id & 16383;
  int e = e16 & 7, l15 = (e16 >> 3) & 15, l4 = (e16 >> 7) & 3,
      kt = (e16 >> 9) & 3, mt = e16 >> 11;
  int c = mt * 16 + l15, k = kt * 32 + l4 * 8 + e;
  float v = (layer ? w3 : w2)[c * 128 + k];
  unsigned short h, l;
  splitbf(v, h, l);
  wsp[layer * 32768 + e16] = h;
  wsp[layer * 32768 + 16384 + e16] = l;
}

// ============================================================
// Kernel A (R6 winner): conv1 -> conv2 -> conv3 (split-bf16 MFMA) ->
// masked-max -> atomicMax pool. grid (NTILES=32, B), 256 thr, 2 blocks/CU.
// ============================================================
__device__ __forceinline__ void mfmaLayer(const unsigned short* __restrict__ Wh,
                                          const unsigned short* __restrict__ Wl,
                                          const float* __restrict__ bias,
                                          const char* XHc, const char* XLc,
                                          int lane, int mt0, f32x4v acc[2][8]) {
  const int l15 = lane & 15, l4 = lane >> 4;
#pragma unroll
  for (int mi = 0; mi < 2; mi++) {
    float4 bv = *(const float4*)(bias + (mt0 + mi) * 16 + l4 * 4);
    f32x4v b4; b4[0] = bv.x; b4[1] = bv.y; b4[2] = bv.z; b4[3] = bv.w;
#pragma unroll
    for (int nt = 0; nt < 8; nt++) acc[mi][nt] = b4;
  }
#pragma unroll
  for (int kt = 0; kt < 4; kt++) {
    bf16x8 ah[2], al[2];
#pragma unroll
    for (int mi = 0; mi < 2; mi++) {
      int off = ((((mt0 + mi) * 4 + kt) * 4 + l4) * 16 + l15) * 8;
      ah[mi] = *(const bf16x8*)(Wh + off);
      al[mi] = *(const bf16x8*)(Wl + off);
    }
    const int kb = (kt * 32 + l4 * 8) * 2;
#pragma unroll
    for (int nt = 0; nt < 8; nt++) {
      const int off = swzb(nt * 16 + l15, kb);
      bf16x8 bh = *(const bf16x8*)(XHc + off);
      bf16x8 bl = *(const bf16x8*)(XLc + off);
#pragma unroll
      for (int mi = 0; mi < 2; mi++) {
        acc[mi][nt] = __builtin_amdgcn_mfma_f32_16x16x32_bf16(ah[mi], bh, acc[mi][nt], 0, 0, 0);
        acc[mi][nt] = __builtin_amdgcn_mfma_f32_16x16x32_bf16(ah[mi], bl, acc[mi][nt], 0, 0, 0);
        acc[mi][nt] = __builtin_amdgcn_mfma_f32_16x16x32_bf16(al[mi], bh, acc[mi][nt], 0, 0, 0);
      }
    }
  }
}

__global__ __launch_bounds__(256, 2) void kA(
    const float* __restrict__ coor, const float* __restrict__ region,
    const float* __restrict__ extents,
    const float* __restrict__ w1, const float* __restrict__ b1,
    const float* __restrict__ b2, const float* __restrict__ b3,
    const unsigned short* __restrict__ wsp,
    unsigned* __restrict__ pool) {
  __shared__ unsigned short XH[128 * 128];  // 32KB (f32 funnel aliases in epilogue)
  __shared__ unsigned short XL[128 * 128];  // 32KB
  __shared__ float reg_s[NM * TILE];        // 4KB
  const int tid = threadIdx.x;
  const int b = blockIdx.y;
  const int t0 = blockIdx.x * TILE;
  const int lane = tid & 63;
  const int wv = tid >> 6;
  char* XHc = (char*)XH;
  char* XLc = (char*)XL;

  {  // stage region tile: 8 rows x 128
    int m = tid >> 5, j = tid & 31;
    float4 v = *(const float4*)(region + ((size_t)b * NM + m) * PTS + t0 + j * 4);
    *(float4*)(reg_s + m * TILE + j * 4) = v;
  }
  {  // layer 1 (K=5): thread = (pt, ch-half); writes Xt bf16 hi/lo
    const int pt = tid & 127;
    const int chh = (tid >> 7) * 64;
    float e0 = extents[b * 3], e1 = extents[b * 3 + 1], e2 = extents[b * 3 + 2];
    float in5[5];
#pragma unroll
    for (int i = 0; i < 5; i++) in5[i] = coor[((size_t)b * 5 + i) * PTS + t0 + pt];
    in5[0] = (in5[0] - 0.5f) * e0;
    in5[1] = (in5[1] - 0.5f) * e1;
    in5[2] = (in5[2] - 0.5f) * e2;
    for (int c8 = 0; c8 < 64; c8 += 8) {
      u16x8 hh, ll;
#pragma unroll
      for (int q = 0; q < 8; q++) {
        int c = chh + c8 + q;
        float s = b1[c];
#pragma unroll
        for (int i = 0; i < 5; i++) s = fmaf(w1[c * 5 + i], in5[i], s);
        s = LEAKY(s);
        unsigned short h, l;
        splitbf(s, h, l);
        hh[q] = h; ll[q] = l;
      }
      int off = swzb(pt, (chh + c8) * 2);
      *(u16x8*)(XHc + off) = hh;
      *(u16x8*)(XLc + off) = ll;
    }
  }
  __syncthreads();

  f32x4v acc[2][8];
  const int mt0 = wv * 2;
  const int l15 = lane & 15, l4 = lane >> 4;

  // layer 2
  mfmaLayer(wsp, wsp + 16384, b2, XHc, XLc, lane, mt0, acc);
  __syncthreads();
  {  // leaky + split + write act2 back to Xt
#pragma unroll
    for (int mi = 0; mi < 2; mi++) {
      const int ch0 = (mt0 + mi) * 16 + l4 * 4;
#pragma unroll
      for (int nt = 0; nt < 8; nt++) {
        u16x4 h4, l4v;
#pragma unroll
        for (int r = 0; r < 4; r++) {
          float s = acc[mi][nt][r];
          s = LEAKY(s);
          unsigned short h, l;
          splitbf(s, h, l);
          h4[r] = h; l4v[r] = l;
        }
        int off = swzb(nt * 16 + l15, ch0 * 2);
        *(u16x4*)(XHc + off) = h4;
        *(u16x4*)(XLc + off) = l4v;
      }
    }
  }
  __syncthreads();
  // layer 3 (bias, no activation)
  mfmaLayer(wsp + 32768, wsp + 49152, b3, XHc, XLc, lane, mt0, acc);
  __syncthreads();  // all reads done; reuse XH as f32 funnel

  {  // region-masked max -> funnel[c*8+m]
    float* funnel = (float*)XH;
#pragma unroll
    for (int m = 0; m < NM; m++) {
      float rv[8];
#pragma unroll
      for (int nt = 0; nt < 8; nt++) rv[nt] = reg_s[m * TILE + nt * 16 + l15];
#pragma unroll
      for (int mi = 0; mi < 2; mi++)
#pragma unroll
        for (int r = 0; r < 4; r++) {
          float mx = acc[mi][0][r] * rv[0];
#pragma unroll
          for (int nt = 1; nt < 8; nt++) mx = fmaxf(mx, acc[mi][nt][r] * rv[nt]);
          mx = fmaxf(mx, __shfl_xor(mx, 1));
          mx = fmaxf(mx, __shfl_xor(mx, 2));
          mx = fmaxf(mx, __shfl_xor(mx, 4));
          mx = fmaxf(mx, __shfl_xor(mx, 8));
          if (l15 == 0) funnel[((mt0 + mi) * 16 + l4 * 4 + r) * 8 + m] = mx;
        }
    }
  }
  __syncthreads();
  {  // order-independent pool: atomicMax of monotone-encoded f32
    const float* fun = (const float*)XH;
    float4 v = *(const float4*)(fun + tid * 4);
    unsigned* pl = pool + (size_t)b * 1024 + tid * 4;
    atomicMax(pl + 0, encf(v.x));
    atomicMax(pl + 1, encf(v.y));
    atomicMax(pl + 2, encf(v.z));
    atomicMax(pl + 3, encf(v.w));
  }
}

// ============================================================
// Kernel C: decode pool -> softmax (4 batches, in LDS) -> per-k sort ->
// GEMM D[b,k,m,o] = sum_c xs[c,m]*w_sp[o,c,k] -> fused gather-sum -> y32.
// grid (32 ktiles of 4, 8 bgroups of 4), 256 thr.
// As stride 516: staging-write bank spread (cc*4+o)%32 -> 2-way (free).
// xs read in compute is wave-uniform -> LDS broadcast (no Bs needed).
// ============================================================
__global__ __launch_bounds__(256) void kC(const unsigned* __restrict__ pool,
                                          const float* __restrict__ w_sp,
                                          float* __restrict__ y32) {
  __shared__ float As[16 * 516];     // 33KB
  __shared__ float xsl[4 * 128 * 8]; // 16KB  [bl][c][m]
  __shared__ int idxL[4][4][8];      // [bl][kk][r]
  const int tid = threadIdx.x;
  const int k0 = blockIdx.x * 4;
  const int bbase = blockIdx.y * 4;
  const int rg = tid & 63, cgq = tid >> 6;

  // decode pool (4 b x 1024) -> xsl
#pragma unroll
  for (int it = 0; it < 4; it++) {
    uint4 v = *(const uint4*)(pool + (size_t)(bbase + it) * 1024 + tid * 4);
    float4 f = {decf(v.x), decf(v.y), decf(v.z), decf(v.w)};
    *(float4*)(xsl + it * 1024 + tid * 4) = f;
  }
  __syncthreads();
  {  // softmax over c per (bl, m): 32 pairs x 8 threads, shfl within 8-lane groups
    int pair = tid >> 3, sub = tid & 7;
    int bl = pair >> 3, m = pair & 7;
    float* base = xsl + bl * 1024 + m;
    float v[16];
#pragma unroll
    for (int j = 0; j < 16; j++) v[j] = base[(sub + 8 * j) * 8];
    float mx = v[0];
#pragma unroll
    for (int j = 1; j < 16; j++) mx = fmaxf(mx, v[j]);
    mx = fmaxf(mx, __shfl_xor(mx, 1));
    mx = fmaxf(mx, __shfl_xor(mx, 2));
    mx = fmaxf(mx, __shfl_xor(mx, 4));
    float s = 0.f;
#pragma unroll
    for (int j = 0; j < 16; j++) { v[j] = expf(v[j] - mx); s += v[j]; }
    s += __shfl_xor(s, 1);
    s += __shfl_xor(s, 2);
    s += __shfl_xor(s, 4);
    float inv = 1.f / s;
#pragma unroll
    for (int j = 0; j < 16; j++) base[(sub + 8 * j) * 8] = v[j] * inv;
  }
  __syncthreads();
  if (tid < 16) {  // sort this block's 4 k-channels per batch
    int bl = tid >> 2, kk = tid & 3;
    float vv[8];
#pragma unroll
    for (int n = 0; n < 8; n++) vv[n] = xsl[bl * 1024 + (k0 + kk) * 8 + n];
    int used = 0;
#pragma unroll
    for (int n = 0; n < 8; n++) {
      int best = 0; float bv = -1.f;
#pragma unroll
      for (int q = 0; q < 8; q++) {
        bool ok = ((used >> q) & 1) == 0;
        if (ok && vv[q] > bv) { bv = vv[q]; best = q; }  // strict > == lowest-index tie-break
      }
      used |= 1 << best;
      idxL[bl][kk][n] = best;
    }
  }

  float acc[8][8];
#pragma unroll
  for (int i = 0; i < 8; i++)
#pragma unroll
    for (int j = 0; j < 8; j++) acc[i][j] = 0.f;

  for (int c0 = 0; c0 < 128; c0 += 16) {
    __syncthreads();
#pragma unroll
    for (int it = 0; it < 8; it++) {
      int q = tid + it * 256;             // 0..2047
      int o = q >> 4, cc = q & 15;
      float4 w = *(const float4*)(w_sp + (size_t)o * 16384 + (size_t)(c0 + cc) * 128 + k0);
      As[cc * 516 + o]       = w.x;
      As[cc * 516 + 128 + o] = w.y;
      As[cc * 516 + 256 + o] = w.z;
      As[cc * 516 + 384 + o] = w.w;
    }
    __syncthreads();
#pragma unroll
    for (int cc = 0; cc < 16; cc++) {
      float4 a0 = *(const float4*)(As + cc * 516 + rg * 4);
      float4 a1 = *(const float4*)(As + cc * 516 + 256 + rg * 4);
      float4 p0 = *(const float4*)(xsl + cgq * 1024 + (c0 + cc) * 8);      // broadcast
      float4 p1 = *(const float4*)(xsl + cgq * 1024 + (c0 + cc) * 8 + 4);  // broadcast
      float av[8] = {a0.x, a0.y, a0.z, a0.w, a1.x, a1.y, a1.z, a1.w};
      float bv[8] = {p0.x, p0.y, p0.z, p0.w, p1.x, p1.y, p1.z, p1.w};
#pragma unroll
      for (int i = 0; i < 8; i++)
#pragma unroll
        for (int j = 0; j < 8; j++) acc[i][j] = fmaf(av[i], bv[j], acc[i][j]);
    }
  }
  // gather-sum epilogue. acc rows: i<4 -> row rg*4+i (kk=rg>>5, o=row&127);
  // i>=4 -> row 256+rg*4+(i-4) (kk=2+(rg>>5)). wave cgq owns batch bbase+cgq.
  const int rgl = rg & 31;
  const int kkA = rg >> 5;
  int msA[8], msB[8];
#pragma unroll
  for (int r = 0; r < 8; r++) {
    msA[r] = idxL[cgq][kkA][r];
    msB[r] = idxL[cgq][2 + kkA][r];
  }
  float yp[4][8];
#pragma unroll
  for (int i4 = 0; i4 < 4; i4++) {
#pragma unroll
    for (int r = 0; r < 8; r++) {
      float v = 0.f;
#pragma unroll
      for (int j = 0; j < 8; j++) {
        v += (j == msA[r]) ? acc[i4][j] : 0.f;
        v += (j == msB[r]) ? acc[i4 + 4][j] : 0.f;
      }
      yp[i4][r] = v;
    }
  }
#pragma unroll
  for (int i4 = 0; i4 < 4; i4++)
#pragma unroll
    for (int r = 0; r < 8; r++) yp[i4][r] += __shfl_xor(yp[i4][r], 32);
  if (rg < 32) {  // lane rg holds o = rg*4+i4, summed over 4 kk
    float* dst = y32 + ((size_t)(bbase + cgq) * 32 + blockIdx.x) * 1024 + rgl * 32;
#pragma unroll
    for (int i4 = 0; i4 < 4; i4++) {
      float4 v0 = {yp[i4][0], yp[i4][1], yp[i4][2], yp[i4][3]};
      float4 v1 = {yp[i4][4], yp[i4][5], yp[i4][6], yp[i4][7]};
      *(float4*)(dst + i4 * 8) = v0;
      *(float4*)(dst + i4 * 8 + 4) = v1;
    }
  }
}

// ============================================================
// Kernel E: assemble y (sum 32 tiles + b_sp + leaky) -> fc1 -> fc2 -> heads.
// grid (B), 1024 thr (16 waves). Wave-per-output passes, coalesced rows.
// ============================================================
__global__ __launch_bounds__(1024) void kE(
    const float* __restrict__ y32, const float* __restrict__ b_sp,
    const float* __restrict__ fc1_w, const float* __restrict__ fc1_b,
    const float* __restrict__ fc2_w, const float* __restrict__ fc2_b,
    const float* __restrict__ fcr_w, const float* __restrict__ fcr_b,
    const float* __restrict__ fct_w, const float* __restrict__ fct_b,
    float* __restrict__ out) {
  __shared__ float yl[1024];
  __shared__ float h1[512];
  __shared__ float h2[256];
  int b = blockIdx.x, tid = threadIdx.x;
  int w = tid >> 6, lane = tid & 63;
  {  // assemble y: thread per feature
    const float* base = y32 + (size_t)b * 32768 + tid;
    float s = 0.f;
#pragma unroll 8
    for (int t = 0; t < 32; t++) s += base[t * 1024];
    s += b_sp[tid >> 3];
    yl[tid] = LEAKY(s);
  }
  __syncthreads();
  {  // fc1: 16 waves x 32 outputs
    const float4* ylv = (const float4*)yl;
    float4 u[4];
#pragma unroll
    for (int r = 0; r < 4; r++) u[r] = ylv[r * 64 + lane];
#pragma unroll 2
    for (int pass = 0; pass < 32; pass++) {
      int o = w * 32 + pass;
      const float4* wr = (const float4*)(fc1_w + (size_t)o * 1024);
      float sa = 0, sb = 0, sc = 0, sd = 0;
#pragma unroll
      for (int r = 0; r < 4; r++) {
        float4 wv = wr[r * 64 + lane];
        sa = fmaf(wv.x, u[r].x, sa); sb = fmaf(wv.y, u[r].y, sb);
        sc = fmaf(wv.z, u[r].z, sc); sd = fmaf(wv.w, u[r].w, sd);
      }
      float s = (sa + sb) + (sc + sd);
#pragma unroll
      for (int d = 1; d < 64; d <<= 1) s += __shfl_xor(s, d);
      if (lane == 0) {
        float t = s + fc1_b[o];
        h1[o] = LEAKY(t);
      }
    }
  }
  __syncthreads();
  {  // fc2: 16 waves x 16 outputs
    const float4* h1v = (const float4*)h1;
    float4 u0 = h1v[lane], u1 = h1v[64 + lane];
#pragma unroll 2
    for (int pass = 0; pass < 16; pass++) {
      int o = w * 16 + pass;
      const float4* wr = (const float4*)(fc2_w + (size_t)o * 512);
      float4 w0 = wr[lane], w1 = wr[64 + lane];
      float sa = fmaf(w0.x, u0.x, 0.f), sb = fmaf(w0.y, u0.y, 0.f);
      float sc = fmaf(w0.z, u0.z, 0.f), sd = fmaf(w0.w, u0.w, 0.f);
      sa = fmaf(w1.x, u1.x, sa); sb = fmaf(w1.y, u1.y, sb);
      sc = fmaf(w1.z, u1.z, sc); sd = fmaf(w1.w, u1.w, sd);
      float s = (sa + sb) + (sc + sd);
#pragma unroll
      for (int d = 1; d < 64; d <<= 1) s += __shfl_xor(s, d);
      if (lane == 0) {
        float t = s + fc2_b[o];
        h2[o] = LEAKY(t);
      }
    }
  }
  __syncthreads();
  if (w < 7) {  // heads: wave-per-output
    bool isrot = w < 4;
    int o = isrot ? w : w - 4;
    const float4* wr = (const float4*)((isrot ? fcr_w : fct_w) + (size_t)o * 256);
    const float4* uv = (const float4*)h2;
    float4 wv = wr[lane];
    float4 u = uv[lane];
    float s = fmaf(wv.x, u.x, fmaf(wv.y, u.y, fmaf(wv.z, u.z, wv.w * u.w)));
#pragma unroll
    for (int d = 1; d < 64; d <<= 1) s += __shfl_xor(s, d);
    if (lane == 0) {
      float t = s + (isrot ? fcr_b[o] : fct_b[o]);
      out[isrot ? (b * 4 + o) : (128 + b * 3 + o)] = t;
    }
  }
}

extern "C" void kernel_launch(void* const* d_in, const int* in_sizes, int n_in,
                              void* d_out, int out_size, void* d_ws, size_t ws_size,
                              hipStream_t stream) {
  const float* coor    = (const float*)d_in[0];
  const float* region  = (const float*)d_in[1];
  const float* extents = (const float*)d_in[2];
  const float* w1 = (const float*)d_in[3];  const float* b1 = (const float*)d_in[4];
  const float* w2 = (const float*)d_in[5];  const float* b2 = (const float*)d_in[6];
  const float* w3 = (const float*)d_in[7];  const float* b3 = (const float*)d_in[8];
  const float* w_sp = (const float*)d_in[9];  const float* b_sp = (const float*)d_in[10];
  const float* fc1_w = (const float*)d_in[11]; const float* fc1_b = (const float*)d_in[12];
  const float* fc2_w = (const float*)d_in[13]; const float* fc2_b = (const float*)d_in[14];
  const float* fcr_w = (const float*)d_in[15]; const float* fcr_b = (const float*)d_in[16];
  const float* fct_w = (const float*)d_in[17]; const float* fct_b = (const float*)d_in[18];

  char* ws = (char*)d_ws;
  unsigned* pool = (unsigned*)(ws + OFF_POOL);
  unsigned short* wsp = (unsigned short*)(ws + OFF_WSP);
  float* y32  = (float*)(ws + OFF_Y32);
  float* out  = (float*)d_out;

  kW<<<dim3(128), 256, 0, stream>>>(w2, w3, wsp, pool);
  kA<<<dim3(NTILES, NBATCH), 256, 0, stream>>>(coor, region, extents,
                                               w1, b1, b2, b3, wsp, pool);
  kC<<<dim3(32, 8), 256, 0, stream>>>(pool, w_sp, y32);
  kE<<<dim3(NBATCH), 1024, 0, stream>>>(y32, b_sp, fc1_w, fc1_b, fc2_w, fc2_b,
                                        fcr_w, fcr_b, fct_w, fct_b, out);
}